// Round 2
// baseline (3377.076 us; speedup 1.0000x reference)
//
#include <hip/hip_runtime.h>
#include <hip/hip_bf16.h>

#define NODES   30000
#define E0N     480000
#define ETOT    510000   // E0N + NODES self loops
#define D0      100
#define WDIM    300      // H*F = 3*100
#define NEG     0.2f

// ---------------- embedding gather: h[i,k] = emb[x[i],k] ----------------
__global__ void gather_emb(const int* __restrict__ x, const float* __restrict__ emb,
                           float* __restrict__ h, int n, int d) {
    int t = blockIdx.x * 256 + threadIdx.x;
    if (t >= n * d) return;
    int i = t / d, k = t - i * d;
    h[t] = emb[x[i] * d + k];
}

// ---------------- CSR build ----------------
__global__ void count_edges(const int* __restrict__ ei, int* __restrict__ counts) {
    int e = blockIdx.x * 256 + threadIdx.x;
    if (e >= ETOT) return;
    int d = (e < E0N) ? ei[E0N + e] : (e - E0N);
    atomicAdd(&counts[d], 1);
}

__global__ __launch_bounds__(1024) void scan_kernel(const int* __restrict__ counts,
                                                    int* __restrict__ offsets, int n) {
    __shared__ int lds[1024];
    const int CH = 32;
    int t = threadIdx.x;
    int base = t * CH;
    int loc[CH];
    int sum = 0;
    #pragma unroll
    for (int i = 0; i < CH; i++) {
        int v = (base + i < n) ? counts[base + i] : 0;
        loc[i] = sum;
        sum += v;
    }
    lds[t] = sum;
    __syncthreads();
    for (int off = 1; off < 1024; off <<= 1) {
        int v = (t >= off) ? lds[t - off] : 0;
        __syncthreads();
        lds[t] += v;
        __syncthreads();
    }
    int ex = (t == 0) ? 0 : lds[t - 1];
    #pragma unroll
    for (int i = 0; i < CH; i++) {
        int idx = base + i;
        if (idx < n) offsets[idx] = ex + loc[i];
    }
    if (t == 0) offsets[n] = lds[1023];
}

__global__ void scatter_edges(const int* __restrict__ ei, const int* __restrict__ offsets,
                              int* __restrict__ cursor, int* __restrict__ csr_src,
                              int* __restrict__ csr_eid) {
    int e = blockIdx.x * 256 + threadIdx.x;
    if (e >= ETOT) return;
    int s, d;
    if (e < E0N) { s = ei[e]; d = ei[E0N + e]; }
    else         { s = e - E0N; d = s; }
    int pos = offsets[d] + atomicAdd(&cursor[d], 1);
    csr_src[pos] = s;
    csr_eid[pos] = e;
}

// ---------------- GEMM: C[M,N] = A[M,K] @ B[K,N] + bias ----------------
#define TM 64
#define TN 64
#define TK 16
__global__ __launch_bounds__(256) void gemm_bias_f32(
    const float* __restrict__ A, const float* __restrict__ B,
    const float* __restrict__ bias, float* __restrict__ C,
    int M, int N, int K) {
    __shared__ float As[TK][TM + 1];
    __shared__ float Bs[TK][TN + 1];
    int tx = threadIdx.x & 15;
    int ty = threadIdx.x >> 4;
    int row0 = blockIdx.y * TM;
    int col0 = blockIdx.x * TN;
    float acc[4][4] = {};
    for (int kt = 0; kt < K; kt += TK) {
        {   // A tile 64x16, store transposed
            int c = threadIdx.x & 15;
            int r = threadIdx.x >> 4;
            #pragma unroll
            for (int i = 0; i < 4; i++) {
                int rr = r + 16 * i;
                int gr = row0 + rr, gc = kt + c;
                As[c][rr] = (gr < M && gc < K) ? A[(size_t)gr * K + gc] : 0.f;
            }
        }
        {   // B tile 16x64
            int c = threadIdx.x & 63;
            int r = threadIdx.x >> 6;
            #pragma unroll
            for (int i = 0; i < 4; i++) {
                int rr = r + 4 * i;
                int gr = kt + rr, gc = col0 + c;
                Bs[rr][c] = (gr < K && gc < N) ? B[(size_t)gr * N + gc] : 0.f;
            }
        }
        __syncthreads();
        #pragma unroll
        for (int k = 0; k < TK; k++) {
            float a[4], b[4];
            #pragma unroll
            for (int i = 0; i < 4; i++) a[i] = As[k][ty * 4 + i];
            #pragma unroll
            for (int j = 0; j < 4; j++) b[j] = Bs[k][tx * 4 + j];
            #pragma unroll
            for (int i = 0; i < 4; i++)
                #pragma unroll
                for (int j = 0; j < 4; j++)
                    acc[i][j] += a[i] * b[j];
        }
        __syncthreads();
    }
    #pragma unroll
    for (int i = 0; i < 4; i++) {
        int gr = row0 + ty * 4 + i;
        if (gr >= M) continue;
        #pragma unroll
        for (int j = 0; j < 4; j++) {
            int gc = col0 + tx * 4 + j;
            if (gc >= N) continue;
            C[(size_t)gr * N + gc] = acc[i][j] + bias[gc];
        }
    }
}

// ---------------- per-edge logits: logit[e,h] = sum_f lrelu(xl[s]+xr[d]) * att[h,f] ----------------
__global__ __launch_bounds__(256) void edge_logits(
    const float* __restrict__ xl, const float* __restrict__ xr,
    const int* __restrict__ ei, const float* __restrict__ att,
    float* __restrict__ logits) {
    int wid = (blockIdx.x * 256 + threadIdx.x) >> 6;
    int lane = threadIdx.x & 63;
    if (wid >= ETOT) return;
    int s, d;
    if (wid < E0N) { s = ei[wid]; d = ei[E0N + wid]; }
    else           { s = wid - E0N; d = s; }
    const float2* pl = (const float2*)(xl + (size_t)s * WDIM);
    const float2* pr = (const float2*)(xr + (size_t)d * WDIM);
    float p0 = 0.f, p1 = 0.f, p2 = 0.f;
    #pragma unroll
    for (int j = 0; j < 3; j++) {
        int idx = lane + 64 * j;
        if (idx < 150) {
            float2 a = pl[idx];
            float2 b = pr[idx];
            int f = idx * 2;
            float w0 = att[f], w1 = att[f + 1];
            float v0 = a.x + b.x; v0 = v0 > 0.f ? v0 : NEG * v0;
            float v1 = a.y + b.y; v1 = v1 > 0.f ? v1 : NEG * v1;
            float v = v0 * w0 + v1 * w1;
            if (f >= 200) p2 += v; else if (f >= 100) p1 += v; else p0 += v;
        }
    }
    #pragma unroll
    for (int off = 32; off; off >>= 1) {
        p0 += __shfl_xor(p0, off, 64);
        p1 += __shfl_xor(p1, off, 64);
        p2 += __shfl_xor(p2, off, 64);
    }
    if (lane == 0) {
        size_t b = (size_t)wid * 3;
        logits[b] = p0; logits[b + 1] = p1; logits[b + 2] = p2;
    }
}

// ---------------- per-dst softmax + aggregate + bias + relu ----------------
__global__ __launch_bounds__(256) void aggregate(
    const float* __restrict__ xl, const float* __restrict__ logits,
    const int* __restrict__ offsets, const int* __restrict__ csr_src,
    const int* __restrict__ csr_eid, const float* __restrict__ bias,
    float* __restrict__ hout) {
    int wid = (blockIdx.x * 256 + threadIdx.x) >> 6;
    int lane = threadIdx.x & 63;
    if (wid >= NODES) return;
    int beg = offsets[wid], end = offsets[wid + 1];
    // pass 1: max per head (all lanes redundant, broadcast loads)
    float m0 = -1e30f, m1 = -1e30f, m2 = -1e30f;
    for (int i = beg; i < end; i++) {
        int eid = csr_eid[i];
        m0 = fmaxf(m0, logits[(size_t)eid * 3]);
        m1 = fmaxf(m1, logits[(size_t)eid * 3 + 1]);
        m2 = fmaxf(m2, logits[(size_t)eid * 3 + 2]);
    }
    // pass 2: sum of exp
    float s0 = 0.f, s1 = 0.f, s2 = 0.f;
    for (int i = beg; i < end; i++) {
        int eid = csr_eid[i];
        s0 += __expf(logits[(size_t)eid * 3]     - m0);
        s1 += __expf(logits[(size_t)eid * 3 + 1] - m1);
        s2 += __expf(logits[(size_t)eid * 3 + 2] - m2);
    }
    float inv0 = 1.f / s0, inv1 = 1.f / s1, inv2 = 1.f / s2;
    // pass 3: weighted gather
    float acc[5] = {0.f, 0.f, 0.f, 0.f, 0.f};
    for (int i = beg; i < end; i++) {
        int eid = csr_eid[i];
        int sid = csr_src[i];
        float a0 = __expf(logits[(size_t)eid * 3]     - m0) * inv0;
        float a1 = __expf(logits[(size_t)eid * 3 + 1] - m1) * inv1;
        float a2 = __expf(logits[(size_t)eid * 3 + 2] - m2) * inv2;
        const float* row = xl + (size_t)sid * WDIM;
        #pragma unroll
        for (int j = 0; j < 5; j++) {
            int f = lane + 64 * j;
            if (f < WDIM) {
                float aa = (f >= 200) ? a2 : ((f >= 100) ? a1 : a0);
                acc[j] += aa * row[f];
            }
        }
    }
    #pragma unroll
    for (int j = 0; j < 5; j++) {
        int f = lane + 64 * j;
        if (f < WDIM) {
            float v = acc[j] + bias[f];
            hout[(size_t)wid * WDIM + f] = fmaxf(v, 0.f);
        }
    }
}

// ---------------- host ----------------
static inline size_t align256(size_t x) { return (x + 255) & ~(size_t)255; }

extern "C" void kernel_launch(void* const* d_in, const int* in_sizes, int n_in,
                              void* d_out, int out_size, void* d_ws, size_t ws_size,
                              hipStream_t stream) {
    const int*   x     = (const int*)d_in[0];
    const int*   ei    = (const int*)d_in[1];   // [2, 480000]
    const float* emb   = (const float*)d_in[2]; // [50,100]
    const float* Wl0   = (const float*)d_in[3]; // [100,300]
    const float* bl0   = (const float*)d_in[4];
    const float* Wr0   = (const float*)d_in[5];
    const float* br0   = (const float*)d_in[6];
    const float* att0  = (const float*)d_in[7]; // [3,100]
    const float* bias0 = (const float*)d_in[8];
    const float* Wl    = (const float*)d_in[9]; // [4,300,300]
    const float* bl    = (const float*)d_in[10];
    const float* Wr    = (const float*)d_in[11];
    const float* br    = (const float*)d_in[12];
    const float* att   = (const float*)d_in[13]; // [4,3,100]
    const float* bias  = (const float*)d_in[14];

    char* ws = (char*)d_ws;
    size_t off = 0;
    float* h      = (float*)(ws + off); off = align256(off + (size_t)NODES * WDIM * 4);
    float* xl     = (float*)(ws + off); off = align256(off + (size_t)NODES * WDIM * 4);
    float* xr     = (float*)(ws + off); off = align256(off + (size_t)NODES * WDIM * 4);
    float* logits = (float*)(ws + off); off = align256(off + (size_t)ETOT * 3 * 4);
    int* counts   = (int*)(ws + off);   off = align256(off + (size_t)NODES * 4);
    int* cursor   = (int*)(ws + off);   off = align256(off + (size_t)NODES * 4);
    int* offsets  = (int*)(ws + off);   off = align256(off + (size_t)(NODES + 1) * 4);
    int* csr_src  = (int*)(ws + off);   off = align256(off + (size_t)ETOT * 4);
    int* csr_eid  = (int*)(ws + off);   off = align256(off + (size_t)ETOT * 4);

    float* out = (float*)d_out;

    // CSR build (edges invariant across layers)
    hipMemsetAsync(counts, 0, (size_t)NODES * 4, stream);
    hipMemsetAsync(cursor, 0, (size_t)NODES * 4, stream);
    count_edges<<<(ETOT + 255) / 256, 256, 0, stream>>>(ei, counts);
    scan_kernel<<<1, 1024, 0, stream>>>(counts, offsets, NODES);
    scatter_edges<<<(ETOT + 255) / 256, 256, 0, stream>>>(ei, offsets, cursor, csr_src, csr_eid);

    // h0 = emb[x]
    gather_emb<<<(NODES * D0 + 255) / 256, 256, 0, stream>>>(x, emb, h, NODES, D0);

    dim3 gemm_grid((WDIM + TN - 1) / TN, (NODES + TM - 1) / TM);
    int edge_blocks = (ETOT + 3) / 4;   // 4 waves per 256-thread block
    int agg_blocks  = (NODES + 3) / 4;

    // layer 0 (K = 100)
    gemm_bias_f32<<<gemm_grid, 256, 0, stream>>>(h, Wl0, bl0, xl, NODES, WDIM, D0);
    gemm_bias_f32<<<gemm_grid, 256, 0, stream>>>(h, Wr0, br0, xr, NODES, WDIM, D0);
    edge_logits<<<edge_blocks, 256, 0, stream>>>(xl, xr, ei, att0, logits);
    aggregate<<<agg_blocks, 256, 0, stream>>>(xl, logits, offsets, csr_src, csr_eid, bias0, h);

    // layers 1..4 (K = 300)
    for (int i = 0; i < 4; i++) {
        const float* Wli = Wl + (size_t)i * WDIM * WDIM;
        const float* Wri = Wr + (size_t)i * WDIM * WDIM;
        float* dst = (i == 3) ? out : h;
        gemm_bias_f32<<<gemm_grid, 256, 0, stream>>>(h, Wli, bl + i * WDIM, xl, NODES, WDIM, WDIM);
        gemm_bias_f32<<<gemm_grid, 256, 0, stream>>>(h, Wri, br + i * WDIM, xr, NODES, WDIM, WDIM);
        edge_logits<<<edge_blocks, 256, 0, stream>>>(xl, xr, ei, att + (size_t)i * WDIM, logits);
        aggregate<<<agg_blocks, 256, 0, stream>>>(xl, logits, offsets, csr_src, csr_eid,
                                                  bias + (size_t)i * WDIM, dst);
    }
}

// Round 3
// 1384.274 us; speedup vs baseline: 2.4396x; 2.4396x over previous
//
#include <hip/hip_runtime.h>

#define NODES   30000
#define E0N     480000
#define ETOT    510000   // E0N + NODES self loops
#define D0      100
#define WDIM    300      // H*F = 3*100
#define NEG     0.2f

// ---------------- embedding gather: h[i,k] = emb[x[i],k] ----------------
__global__ void gather_emb(const int* __restrict__ x, const float* __restrict__ emb,
                           float* __restrict__ h, int n, int d) {
    int t = blockIdx.x * 256 + threadIdx.x;
    if (t >= n * d) return;
    int i = t / d, k = t - i * d;
    h[t] = emb[x[i] * d + k];
}

// ---------------- CSR build ----------------
__global__ void count_edges(const int* __restrict__ ei, int* __restrict__ counts) {
    int e = blockIdx.x * 256 + threadIdx.x;
    if (e >= ETOT) return;
    int d = (e < E0N) ? ei[E0N + e] : (e - E0N);
    atomicAdd(&counts[d], 1);
}

__global__ __launch_bounds__(1024) void scan_kernel(const int* __restrict__ counts,
                                                    int* __restrict__ offsets, int n) {
    __shared__ int lds[1024];
    const int CH = 32;
    int t = threadIdx.x;
    int base = t * CH;
    int loc[CH];
    int sum = 0;
    #pragma unroll
    for (int i = 0; i < CH; i++) {
        int v = (base + i < n) ? counts[base + i] : 0;
        loc[i] = sum;
        sum += v;
    }
    lds[t] = sum;
    __syncthreads();
    for (int off = 1; off < 1024; off <<= 1) {
        int v = (t >= off) ? lds[t - off] : 0;
        __syncthreads();
        lds[t] += v;
        __syncthreads();
    }
    int ex = (t == 0) ? 0 : lds[t - 1];
    #pragma unroll
    for (int i = 0; i < CH; i++) {
        int idx = base + i;
        if (idx < n) offsets[idx] = ex + loc[i];
    }
    if (t == 0) offsets[n] = lds[1023];
}

__global__ void scatter_edges(const int* __restrict__ ei, const int* __restrict__ offsets,
                              int* __restrict__ cursor, int* __restrict__ csr_src) {
    int e = blockIdx.x * 256 + threadIdx.x;
    if (e >= ETOT) return;
    int s, d;
    if (e < E0N) { s = ei[e]; d = ei[E0N + e]; }
    else         { s = e - E0N; d = s; }
    int pos = offsets[d] + atomicAdd(&cursor[d], 1);
    csr_src[pos] = s;
}

// ---------------- fused dual GEMM: [Cl|Cr] = A @ [Bl|Br] + [bl|br] ----------------
// A: [M,K] f32, Bl/Br: [K,300] f32, Cl/Cr: [M,300] f32. Effective N = 600.
#define TM 64
#define TN 64
#define TK 16
__global__ __launch_bounds__(256) void gemm_dual(
    const float* __restrict__ A,
    const float* __restrict__ Bl, const float* __restrict__ Br,
    const float* __restrict__ bl, const float* __restrict__ br,
    float* __restrict__ Cl, float* __restrict__ Cr,
    int M, int K) {
    __shared__ __align__(16) float As[TK][TM + 4];  // transposed A tile
    __shared__ __align__(16) float Bs[TK][TN + 4];
    int tid = threadIdx.x;
    int tx = tid & 15;
    int ty = tid >> 4;
    int row0 = blockIdx.y * TM;
    int col0 = blockIdx.x * TN;   // 0..576 over effective N=600
    float acc[4][4] = {};

    for (int kt = 0; kt < K; kt += TK) {
        // A tile: 64 rows x 16 cols = 256 float4 (one per thread), store transposed
        {
            int r  = tid >> 2;          // 0..63
            int c4 = tid & 3;           // 0..3
            int gr = row0 + r;
            int kc = kt + c4 * 4;
            float4 a = make_float4(0.f, 0.f, 0.f, 0.f);
            if (gr < M && kc + 3 < K)
                a = *(const float4*)(A + (size_t)gr * K + kc);
            As[c4 * 4 + 0][r] = a.x;
            As[c4 * 4 + 1][r] = a.y;
            As[c4 * 4 + 2][r] = a.z;
            As[c4 * 4 + 3][r] = a.w;
        }
        // B tile: 16 rows x 64 cols = 256 float4 (one per thread)
        {
            int r  = tid >> 4;          // 0..15
            int c4 = tid & 15;          // 0..15
            int grow = kt + r;
            int gcol = col0 + c4 * 4;   // multiple of 4; never straddles 300
            float4 b = make_float4(0.f, 0.f, 0.f, 0.f);
            if (grow < K) {
                if (gcol + 3 < WDIM)
                    b = *(const float4*)(Bl + (size_t)grow * WDIM + gcol);
                else if (gcol >= WDIM && gcol + 3 < 2 * WDIM)
                    b = *(const float4*)(Br + (size_t)grow * WDIM + gcol - WDIM);
            }
            *(float4*)(&Bs[r][c4 * 4]) = b;
        }
        __syncthreads();
        #pragma unroll
        for (int k = 0; k < TK; k++) {
            float4 a4 = *(const float4*)(&As[k][ty * 4]);
            float4 b4 = *(const float4*)(&Bs[k][tx * 4]);
            float a[4] = {a4.x, a4.y, a4.z, a4.w};
            float b[4] = {b4.x, b4.y, b4.z, b4.w};
            #pragma unroll
            for (int i = 0; i < 4; i++)
                #pragma unroll
                for (int j = 0; j < 4; j++)
                    acc[i][j] += a[i] * b[j];
        }
        __syncthreads();
    }

    // epilogue: add bias, store float4 to Cl or Cr
    int gc = col0 + tx * 4;   // multiple of 4, never straddles 300
    if (gc + 3 < 2 * WDIM) {
        bool left = gc < WDIM;
        int cc = left ? gc : gc - WDIM;
        const float* bb = left ? bl : br;
        float4 bv = *(const float4*)(bb + cc);
        float* C = left ? Cl : Cr;
        #pragma unroll
        for (int i = 0; i < 4; i++) {
            int gr = row0 + ty * 4 + i;
            if (gr >= M) continue;
            float4 res;
            res.x = acc[i][0] + bv.x;
            res.y = acc[i][1] + bv.y;
            res.z = acc[i][2] + bv.z;
            res.w = acc[i][3] + bv.w;
            *(float4*)(C + (size_t)gr * WDIM + cc) = res;
        }
    }
}

// ---------------- fused edge-score + online-softmax + aggregate ----------------
// One wave per dst node. xr[d] row resident in regs; single pass over CSR edges.
__global__ __launch_bounds__(256) void gat_edge_agg(
    const float* __restrict__ xl, const float* __restrict__ xr,
    const int* __restrict__ offsets, const int* __restrict__ csr_src,
    const float* __restrict__ att, const float* __restrict__ bias,
    float* __restrict__ hout) {
    int wid = (blockIdx.x * 256 + threadIdx.x) >> 6;
    int lane = threadIdx.x & 63;
    if (wid >= NODES) return;

    // resident per-lane slices: features f = lane + 64*j, j=0..4
    float xrv[5], aw[5];
    #pragma unroll
    for (int j = 0; j < 5; j++) {
        int f = lane + 64 * j;
        xrv[j] = (f < WDIM) ? xr[(size_t)wid * WDIM + f] : 0.f;
        aw[j]  = (f < WDIM) ? att[f] : 0.f;
    }

    float m0 = -3e38f, m1 = -3e38f, m2 = -3e38f;
    float s0 = 0.f, s1 = 0.f, s2 = 0.f;
    float acc[5] = {0.f, 0.f, 0.f, 0.f, 0.f};

    int beg = offsets[wid], end = offsets[wid + 1];
    for (int i = beg; i < end; i++) {
        int sid = csr_src[i];
        const float* row = xl + (size_t)sid * WDIM;
        float v[5];
        float p0 = 0.f, p1 = 0.f, p2 = 0.f;
        #pragma unroll
        for (int j = 0; j < 5; j++) {
            int f = lane + 64 * j;
            v[j] = (f < WDIM) ? row[f] : 0.f;
            float t = v[j] + xrv[j];
            t = t > 0.f ? t : NEG * t;
            float pv = t * aw[j];
            if (f >= 200)      p2 += pv;
            else if (f >= 100) p1 += pv;
            else               p0 += pv;
        }
        #pragma unroll
        for (int off = 32; off; off >>= 1) {
            p0 += __shfl_xor(p0, off, 64);
            p1 += __shfl_xor(p1, off, 64);
            p2 += __shfl_xor(p2, off, 64);
        }
        // online softmax update per head
        float nm0 = fmaxf(m0, p0), nm1 = fmaxf(m1, p1), nm2 = fmaxf(m2, p2);
        float e0 = __expf(m0 - nm0), e1 = __expf(m1 - nm1), e2 = __expf(m2 - nm2);
        float c0 = __expf(p0 - nm0), c1 = __expf(p1 - nm1), c2 = __expf(p2 - nm2);
        s0 = s0 * e0 + c0; m0 = nm0;
        s1 = s1 * e1 + c1; m1 = nm1;
        s2 = s2 * e2 + c2; m2 = nm2;
        #pragma unroll
        for (int j = 0; j < 5; j++) {
            int f = lane + 64 * j;
            float e = (f >= 200) ? e2 : ((f >= 100) ? e1 : e0);
            float c = (f >= 200) ? c2 : ((f >= 100) ? c1 : c0);
            acc[j] = acc[j] * e + c * v[j];
        }
    }

    float i0 = 1.f / s0, i1 = 1.f / s1, i2 = 1.f / s2;
    #pragma unroll
    for (int j = 0; j < 5; j++) {
        int f = lane + 64 * j;
        if (f < WDIM) {
            float aa = (f >= 200) ? i2 : ((f >= 100) ? i1 : i0);
            float o = acc[j] * aa + bias[f];
            hout[(size_t)wid * WDIM + f] = fmaxf(o, 0.f);
        }
    }
}

// ---------------- host ----------------
static inline size_t align256(size_t x) { return (x + 255) & ~(size_t)255; }

extern "C" void kernel_launch(void* const* d_in, const int* in_sizes, int n_in,
                              void* d_out, int out_size, void* d_ws, size_t ws_size,
                              hipStream_t stream) {
    const int*   x     = (const int*)d_in[0];
    const int*   ei    = (const int*)d_in[1];   // [2, 480000]
    const float* emb   = (const float*)d_in[2]; // [50,100]
    const float* Wl0   = (const float*)d_in[3]; // [100,300]
    const float* bl0   = (const float*)d_in[4];
    const float* Wr0   = (const float*)d_in[5];
    const float* br0   = (const float*)d_in[6];
    const float* att0  = (const float*)d_in[7]; // [3,100]
    const float* bias0 = (const float*)d_in[8];
    const float* Wl    = (const float*)d_in[9]; // [4,300,300]
    const float* bl    = (const float*)d_in[10];
    const float* Wr    = (const float*)d_in[11];
    const float* br    = (const float*)d_in[12];
    const float* att   = (const float*)d_in[13]; // [4,3,100]
    const float* bias  = (const float*)d_in[14];

    char* ws = (char*)d_ws;
    size_t off = 0;
    float* h      = (float*)(ws + off); off = align256(off + (size_t)NODES * WDIM * 4);
    float* xlb    = (float*)(ws + off); off = align256(off + (size_t)NODES * WDIM * 4);
    float* xrb    = (float*)(ws + off); off = align256(off + (size_t)NODES * WDIM * 4);
    int* counts   = (int*)(ws + off);   off = align256(off + (size_t)NODES * 4);
    int* cursor   = (int*)(ws + off);   off = align256(off + (size_t)NODES * 4);
    int* offsets  = (int*)(ws + off);   off = align256(off + (size_t)(NODES + 1) * 4);
    int* csr_src  = (int*)(ws + off);   off = align256(off + (size_t)ETOT * 4);

    float* out = (float*)d_out;

    // CSR build (edges invariant across layers)
    hipMemsetAsync(counts, 0, (size_t)NODES * 4, stream);
    hipMemsetAsync(cursor, 0, (size_t)NODES * 4, stream);
    count_edges<<<(ETOT + 255) / 256, 256, 0, stream>>>(ei, counts);
    scan_kernel<<<1, 1024, 0, stream>>>(counts, offsets, NODES);
    scatter_edges<<<(ETOT + 255) / 256, 256, 0, stream>>>(ei, offsets, cursor, csr_src);

    // h0 = emb[x]
    gather_emb<<<(NODES * D0 + 255) / 256, 256, 0, stream>>>(x, emb, h, NODES, D0);

    dim3 gemm_grid((2 * WDIM + TN - 1) / TN, (NODES + TM - 1) / TM);  // 10 x 469
    int agg_blocks = (NODES + 3) / 4;   // 4 waves per 256-thread block

    // layer 0 (K = 100)
    gemm_dual<<<gemm_grid, 256, 0, stream>>>(h, Wl0, Wr0, bl0, br0, xlb, xrb, NODES, D0);
    gat_edge_agg<<<agg_blocks, 256, 0, stream>>>(xlb, xrb, offsets, csr_src, att0, bias0, h);

    // layers 1..4 (K = 300)
    for (int i = 0; i < 4; i++) {
        const float* Wli = Wl + (size_t)i * WDIM * WDIM;
        const float* Wri = Wr + (size_t)i * WDIM * WDIM;
        float* dst = (i == 3) ? out : h;
        gemm_dual<<<gemm_grid, 256, 0, stream>>>(h, Wli, Wri, bl + i * WDIM, br + i * WDIM,
                                                 xlb, xrb, NODES, WDIM);
        gat_edge_agg<<<agg_blocks, 256, 0, stream>>>(xlb, xrb, offsets, csr_src,
                                                     att + (size_t)i * WDIM,
                                                     bias + (size_t)i * WDIM, dst);
    }
}

// Round 4
// 1004.205 us; speedup vs baseline: 3.3629x; 1.3785x over previous
//
#include <hip/hip_runtime.h>

#define NODES   30000
#define E0N     480000
#define ETOT    510000   // E0N + NODES self loops
#define D0      100
#define WDIM    300      // H*F = 3*100
#define NW      600      // dual output width
#define NEG     0.2f

typedef __bf16 bf16x8 __attribute__((ext_vector_type(8)));
typedef float  f32x4  __attribute__((ext_vector_type(4)));

// ---------------- embedding gather: h[i,k] = emb[x[i],k] ----------------
__global__ void gather_emb(const int* __restrict__ x, const float* __restrict__ emb,
                           float* __restrict__ h, int n, int d) {
    int t = blockIdx.x * 256 + threadIdx.x;
    if (t >= n * d) return;
    int i = t / d, k = t - i * d;
    h[t] = emb[x[i] * d + k];
}

// ---------------- CSR build ----------------
__global__ void count_edges(const int* __restrict__ ei, int* __restrict__ counts) {
    int e = blockIdx.x * 256 + threadIdx.x;
    if (e >= ETOT) return;
    int d = (e < E0N) ? ei[E0N + e] : (e - E0N);
    atomicAdd(&counts[d], 1);
}

__global__ __launch_bounds__(1024) void scan_kernel(const int* __restrict__ counts,
                                                    int* __restrict__ offsets, int n) {
    __shared__ int lds[1024];
    const int CH = 32;
    int t = threadIdx.x;
    int base = t * CH;
    int loc[CH];
    int sum = 0;
    #pragma unroll
    for (int i = 0; i < CH; i++) {
        int v = (base + i < n) ? counts[base + i] : 0;
        loc[i] = sum;
        sum += v;
    }
    lds[t] = sum;
    __syncthreads();
    for (int off = 1; off < 1024; off <<= 1) {
        int v = (t >= off) ? lds[t - off] : 0;
        __syncthreads();
        lds[t] += v;
        __syncthreads();
    }
    int ex = (t == 0) ? 0 : lds[t - 1];
    #pragma unroll
    for (int i = 0; i < CH; i++) {
        int idx = base + i;
        if (idx < n) offsets[idx] = ex + loc[i];
    }
    if (t == 0) offsets[n] = lds[1023];
}

__global__ void scatter_edges(const int* __restrict__ ei, const int* __restrict__ offsets,
                              int* __restrict__ cursor, int* __restrict__ csr_src) {
    int e = blockIdx.x * 256 + threadIdx.x;
    if (e >= ETOT) return;
    int s, d;
    if (e < E0N) { s = ei[e]; d = ei[E0N + e]; }
    else         { s = e - E0N; d = s; }
    int pos = offsets[d] + atomicAdd(&cursor[d], 1);
    csr_src[pos] = s;
}

// ---------------- B fragment pre-split (hi/lo bf16, MFMA-fragment-linear) ----
// Layout: [s][n16][part][lane] of bf16x8; element j of lane l at (s,n16):
//   B[k][c], k = s*32 + (l>>4)*8 + j, c = n16*16 + (l&15)   (zero-padded)
__global__ void make_bfrag(const float* __restrict__ Bl, const float* __restrict__ Br,
                           bf16x8* __restrict__ out, int K, int ksteps) {
    int t = blockIdx.x * 256 + threadIdx.x;
    int total = ksteps * 40 * 64;
    if (t >= total) return;
    int lane = t & 63;
    int n16  = (t >> 6) % 40;
    int s    = t / (64 * 40);
    int c = n16 * 16 + (lane & 15);
    union { bf16x8 v; __bf16 e[8]; } hi, lo;
    #pragma unroll
    for (int j = 0; j < 8; j++) {
        int k = s * 32 + ((lane >> 4) * 8) + j;
        float x = 0.f;
        if (k < K && c < NW)
            x = (c < WDIM) ? Bl[(size_t)k * WDIM + c] : Br[(size_t)k * WDIM + c - WDIM];
        __bf16 h = (__bf16)x;
        hi.e[j] = h;
        lo.e[j] = (__bf16)(x - (float)h);
    }
    size_t base = ((size_t)(s * 40 + n16) * 2) * 64 + lane;
    out[base]      = hi.v;
    out[base + 64] = lo.v;
}

// ---------------- MFMA dual GEMM: [Cl|Cr] = A @ [Bl|Br] + [bl|br] ----------
// split-bf16 (hi+lo), 4 cross-product MFMAs, f32 accumulate.
// Block tile 128x128, 4 waves (2x2), K-step 32.
__global__ __launch_bounds__(256) void gemm_mfma(
    const float* __restrict__ A, const bf16x8* __restrict__ Bfrag,
    const float* __restrict__ bl, const float* __restrict__ br,
    float* __restrict__ Cl, float* __restrict__ Cr,
    int M, int K, int ksteps) {

    __shared__ bf16x8 Alds[8][2][64];   // [m16][part][slot]
    __shared__ bf16x8 Blds[8][2][64];   // [n16][part][slot]

    int id = blockIdx.x;
    // XCD-swizzle: the 5 col-blocks sharing one A-panel get ids ≡ (mod 8) -> same XCD
    int mb = (id & 7) + 8 * (id / 40);
    int cb = (id >> 3) % 5;
    if (mb >= 235) return;

    int tid  = threadIdx.x;
    int lane = tid & 63;
    int wid  = tid >> 6;
    int wm = wid >> 1, wn = wid & 1;
    int row0 = mb * 128;

    f32x4 acc[4][4] = {};

    for (int s = 0; s < ksteps; s++) {
        int kt = s * 32;
        // ---- stage A: 512 (m16,slot) tuples, 2 per thread, f32 -> hi/lo bf16
        #pragma unroll
        for (int u0 = 0; u0 < 2; u0++) {
            int u = u0 * 256 + tid;
            int m16  = u >> 6;
            int slot = u & 63;
            int kh = slot >> 4, rl = slot & 15;
            int gr = row0 + m16 * 16 + rl;
            int gc = kt + kh * 8;
            float4 v0 = make_float4(0.f,0.f,0.f,0.f), v1 = v0;
            if (gr < M) {
                const float* ap = A + (size_t)gr * K + gc;
                if (gc + 4 <= K) v0 = *(const float4*)ap;
                if (gc + 8 <= K) v1 = *(const float4*)(ap + 4);
            }
            union { bf16x8 v; __bf16 e[8]; } hi, lo;
            const float* xs0 = (const float*)&v0;
            const float* xs1 = (const float*)&v1;
            #pragma unroll
            for (int j = 0; j < 8; j++) {
                float x = (j < 4) ? xs0[j] : xs1[j - 4];
                __bf16 h = (__bf16)x;
                hi.e[j] = h;
                lo.e[j] = (__bf16)(x - (float)h);
            }
            Alds[m16][0][slot] = hi.v;
            Alds[m16][1][slot] = lo.v;
        }
        // ---- stage B: 16KB linear copy from pre-split fragments
        {
            const float4* bsrc = (const float4*)(Bfrag + ((size_t)(s * 40 + cb * 8) * 2) * 64);
            float4* bdst = (float4*)&Blds[0][0][0];
            #pragma unroll
            for (int c = 0; c < 4; c++)
                bdst[c * 256 + tid] = bsrc[c * 256 + tid];
        }
        __syncthreads();

        bf16x8 af[4][2], bfr[4][2];
        #pragma unroll
        for (int m = 0; m < 4; m++) {
            af[m][0] = Alds[wm * 4 + m][0][lane];
            af[m][1] = Alds[wm * 4 + m][1][lane];
        }
        #pragma unroll
        for (int n = 0; n < 4; n++) {
            bfr[n][0] = Blds[wn * 4 + n][0][lane];
            bfr[n][1] = Blds[wn * 4 + n][1][lane];
        }
        #pragma unroll
        for (int m = 0; m < 4; m++)
            #pragma unroll
            for (int n = 0; n < 4; n++) {
                acc[m][n] = __builtin_amdgcn_mfma_f32_16x16x32_bf16(af[m][1], bfr[n][1], acc[m][n], 0, 0, 0);
                acc[m][n] = __builtin_amdgcn_mfma_f32_16x16x32_bf16(af[m][1], bfr[n][0], acc[m][n], 0, 0, 0);
                acc[m][n] = __builtin_amdgcn_mfma_f32_16x16x32_bf16(af[m][0], bfr[n][1], acc[m][n], 0, 0, 0);
                acc[m][n] = __builtin_amdgcn_mfma_f32_16x16x32_bf16(af[m][0], bfr[n][0], acc[m][n], 0, 0, 0);
            }
        __syncthreads();
    }

    // ---- epilogue: D row=(lane>>4)*4+reg, col=lane&15 ; add bias, store
    int r0 = row0 + wm * 64;
    int c0 = cb * 128 + wn * 64;
    #pragma unroll
    for (int m = 0; m < 4; m++)
        #pragma unroll
        for (int n = 0; n < 4; n++) {
            #pragma unroll
            for (int reg = 0; reg < 4; reg++) {
                int gr = r0 + m * 16 + (lane >> 4) * 4 + reg;
                int gc = c0 + n * 16 + (lane & 15);
                if (gr < M && gc < NW) {
                    bool left = gc < WDIM;
                    int cc = left ? gc : gc - WDIM;
                    float v = acc[m][n][reg] + (left ? bl[cc] : br[cc]);
                    (left ? Cl : Cr)[(size_t)gr * WDIM + cc] = v;
                }
            }
        }
}

// ---------------- fused edge-score + online-softmax + aggregate ----------------
__global__ __launch_bounds__(256) void gat_edge_agg(
    const float* __restrict__ xl, const float* __restrict__ xr,
    const int* __restrict__ offsets, const int* __restrict__ csr_src,
    const float* __restrict__ att, const float* __restrict__ bias,
    float* __restrict__ hout) {
    int wid = (blockIdx.x * 256 + threadIdx.x) >> 6;
    int lane = threadIdx.x & 63;
    if (wid >= NODES) return;

    float xrv[5], aw[5];
    #pragma unroll
    for (int j = 0; j < 5; j++) {
        int f = lane + 64 * j;
        xrv[j] = (f < WDIM) ? xr[(size_t)wid * WDIM + f] : 0.f;
        aw[j]  = (f < WDIM) ? att[f] : 0.f;
    }

    float m0 = -3e38f, m1 = -3e38f, m2 = -3e38f;
    float s0 = 0.f, s1 = 0.f, s2 = 0.f;
    float acc[5] = {0.f, 0.f, 0.f, 0.f, 0.f};

    int beg = offsets[wid], end = offsets[wid + 1];
    for (int i = beg; i < end; i++) {
        int sid = csr_src[i];
        const float* row = xl + (size_t)sid * WDIM;
        float v[5];
        float p0 = 0.f, p1 = 0.f, p2 = 0.f;
        #pragma unroll
        for (int j = 0; j < 5; j++) {
            int f = lane + 64 * j;
            v[j] = (f < WDIM) ? row[f] : 0.f;
            float t = v[j] + xrv[j];
            t = t > 0.f ? t : NEG * t;
            float pv = t * aw[j];
            if (f >= 200)      p2 += pv;
            else if (f >= 100) p1 += pv;
            else               p0 += pv;
        }
        #pragma unroll
        for (int off = 32; off; off >>= 1) {
            p0 += __shfl_xor(p0, off, 64);
            p1 += __shfl_xor(p1, off, 64);
            p2 += __shfl_xor(p2, off, 64);
        }
        float nm0 = fmaxf(m0, p0), nm1 = fmaxf(m1, p1), nm2 = fmaxf(m2, p2);
        float e0 = __expf(m0 - nm0), e1 = __expf(m1 - nm1), e2 = __expf(m2 - nm2);
        float c0 = __expf(p0 - nm0), c1 = __expf(p1 - nm1), c2 = __expf(p2 - nm2);
        s0 = s0 * e0 + c0; m0 = nm0;
        s1 = s1 * e1 + c1; m1 = nm1;
        s2 = s2 * e2 + c2; m2 = nm2;
        #pragma unroll
        for (int j = 0; j < 5; j++) {
            int f = lane + 64 * j;
            float e = (f >= 200) ? e2 : ((f >= 100) ? e1 : e0);
            float c = (f >= 200) ? c2 : ((f >= 100) ? c1 : c0);
            acc[j] = acc[j] * e + c * v[j];
        }
    }

    float i0 = 1.f / s0, i1 = 1.f / s1, i2 = 1.f / s2;
    #pragma unroll
    for (int j = 0; j < 5; j++) {
        int f = lane + 64 * j;
        if (f < WDIM) {
            float aa = (f >= 200) ? i2 : ((f >= 100) ? i1 : i0);
            float o = acc[j] * aa + bias[f];
            hout[(size_t)wid * WDIM + f] = fmaxf(o, 0.f);
        }
    }
}

// ---------------- host ----------------
static inline size_t align256(size_t x) { return (x + 255) & ~(size_t)255; }

extern "C" void kernel_launch(void* const* d_in, const int* in_sizes, int n_in,
                              void* d_out, int out_size, void* d_ws, size_t ws_size,
                              hipStream_t stream) {
    const int*   x     = (const int*)d_in[0];
    const int*   ei    = (const int*)d_in[1];
    const float* emb   = (const float*)d_in[2];
    const float* Wl0   = (const float*)d_in[3];
    const float* bl0   = (const float*)d_in[4];
    const float* Wr0   = (const float*)d_in[5];
    const float* br0   = (const float*)d_in[6];
    const float* att0  = (const float*)d_in[7];
    const float* bias0 = (const float*)d_in[8];
    const float* Wl    = (const float*)d_in[9];
    const float* bl    = (const float*)d_in[10];
    const float* Wr    = (const float*)d_in[11];
    const float* br    = (const float*)d_in[12];
    const float* att   = (const float*)d_in[13];
    const float* bias  = (const float*)d_in[14];

    char* ws = (char*)d_ws;
    size_t off = 0;
    float* h      = (float*)(ws + off); off = align256(off + (size_t)NODES * WDIM * 4);
    float* xlb    = (float*)(ws + off); off = align256(off + (size_t)NODES * WDIM * 4);
    float* xrb    = (float*)(ws + off); off = align256(off + (size_t)NODES * WDIM * 4);
    int* counts   = (int*)(ws + off);   off = align256(off + (size_t)NODES * 4);
    int* cursor   = (int*)(ws + off);   off = align256(off + (size_t)NODES * 4);
    int* offsets  = (int*)(ws + off);   off = align256(off + (size_t)(NODES + 1) * 4);
    int* csr_src  = (int*)(ws + off);   off = align256(off + (size_t)ETOT * 4);
    bf16x8* bfrag = (bf16x8*)(ws + off); off = align256(off + (size_t)10 * 40 * 2 * 64 * 16);

    float* out = (float*)d_out;

    // CSR build (edges invariant across layers)
    hipMemsetAsync(counts, 0, (size_t)NODES * 4, stream);
    hipMemsetAsync(cursor, 0, (size_t)NODES * 4, stream);
    count_edges<<<(ETOT + 255) / 256, 256, 0, stream>>>(ei, counts);
    scan_kernel<<<1, 1024, 0, stream>>>(counts, offsets, NODES);
    scatter_edges<<<(ETOT + 255) / 256, 256, 0, stream>>>(ei, offsets, cursor, csr_src);

    // h0 = emb[x]
    gather_emb<<<(NODES * D0 + 255) / 256, 256, 0, stream>>>(x, emb, h, NODES, D0);

    int agg_blocks = (NODES + 3) / 4;

    // layer 0 (K = 100, ksteps = 4)
    {
        int ks = 4;
        int bf_total = ks * 40 * 64;
        make_bfrag<<<(bf_total + 255) / 256, 256, 0, stream>>>(Wl0, Wr0, bfrag, D0, ks);
        gemm_mfma<<<1200, 256, 0, stream>>>(h, bfrag, bl0, br0, xlb, xrb, NODES, D0, ks);
        gat_edge_agg<<<agg_blocks, 256, 0, stream>>>(xlb, xrb, offsets, csr_src, att0, bias0, h);
    }

    // layers 1..4 (K = 300, ksteps = 10)
    for (int i = 0; i < 4; i++) {
        const float* Wli = Wl + (size_t)i * WDIM * WDIM;
        const float* Wri = Wr + (size_t)i * WDIM * WDIM;
        float* dst = (i == 3) ? out : h;
        int ks = 10;
        int bf_total = ks * 40 * 64;
        make_bfrag<<<(bf_total + 255) / 256, 256, 0, stream>>>(Wli, Wri, bfrag, WDIM, ks);
        gemm_mfma<<<1200, 256, 0, stream>>>(h, bfrag, bl + i * WDIM, br + i * WDIM,
                                            xlb, xrb, NODES, WDIM, ks);
        gat_edge_agg<<<agg_blocks, 256, 0, stream>>>(xlb, xrb, offsets, csr_src,
                                                     att + (size_t)i * WDIM,
                                                     bias + (size_t)i * WDIM, dst);
    }
}